// Round 12
// baseline (66.477 us; speedup 1.0000x reference)
//
#include <hip/hip_runtime.h>
#include <stdint.h>

#define NFEAT 16
#define NCOLS 969            // 1 bias + 16 deg1 + 136 deg2 + 816 deg3
#define NROWS 65536
#define PROWS 16             // rows per half-pass (double-buffered)
#define NPASS 16             // 256 rows per block / 16
#define PASS_F4 (PROWS * NCOLS / 4)   // 3876 float4 groups per half-pass

typedef float floatx4 __attribute__((ext_vector_type(4)));

// ---------------------------------------------------------------------------
// Static compute of cols [CBASE, CEND) of one row into packed LDS row.
// All 969 columns emitted in sklearn/jax reference order (verified absmax 0.0
// R1/R3-R11); out-of-range emits are compile-time dead. Scalar ds_write_b32:
// packed stride 969 -> banks (9*row + col) % 32, stride 9 coprime with 32 ->
// the 16 rows hit 16 distinct banks: conflict-free.
// NOTE: no VGPR cap anywhere (R7/R8/R9 spill lesson).
// ---------------------------------------------------------------------------
template<int CBASE, int CEND>
__device__ __forceinline__ void compute_range(const float* xr, float* ldsrow) {
    int col = 0;
#define EMIT(P) do { if (col >= CBASE && col < CEND) ldsrow[col] = (P); ++col; } while (0)
    EMIT(1.0f);                                   // bias
    #pragma unroll
    for (int i = 0; i < NFEAT; ++i) EMIT(xr[i]);  // degree 1
    #pragma unroll
    for (int i = 0; i < NFEAT; ++i)               // degree 2
        #pragma unroll
        for (int j = i; j < NFEAT; ++j) EMIT(xr[i] * xr[j]);
    #pragma unroll
    for (int i = 0; i < NFEAT; ++i)               // degree 3 (reuses x_i*x_j via CSE)
        #pragma unroll
        for (int j = i; j < NFEAT; ++j)
            #pragma unroll
            for (int k = j; k < NFEAT; ++k) EMIT((xr[i] * xr[j]) * xr[k]);
#undef EMIT
}

__device__ __forceinline__ void compute_dispatch(int range, const float* xr, float* ldsrow) {
    switch (range) {   // uniform per 16-lane group; 4 serial bodies per wave
        case 0: compute_range<  0, 124>(xr, ldsrow); break;
        case 1: compute_range<124, 248>(xr, ldsrow); break;
        case 2: compute_range<248, 372>(xr, ldsrow); break;
        case 3: compute_range<372, 496>(xr, ldsrow); break;
        case 4: compute_range<496, 620>(xr, ldsrow); break;
        case 5: compute_range<620, 744>(xr, ldsrow); break;
        case 6: compute_range<744, 868>(xr, ldsrow); break;
        case 7: compute_range<868, 969>(xr, ldsrow); break;
    }
}

// ---------------------------------------------------------------------------
// Producer/consumer wave-specialized kernel.
//   waves 0-1 (tid 0..127):  compute 16-row half-passes into lds[p&1]
//   waves 2-3 (tid 128..255): flat-copy lds[(p)&1] -> out (b128 reads,
//                             dwordx4 stores) — HBM write pipe never idles.
// Barrier sequence: both sides execute exactly NPASS s_barriers.
//   barrier k: producers have finished writing buf k&1 (lgkmcnt(0));
//              consumers are about to read buf k&1. Producers then compute
//              buf (k+1)&1 while consumers drain buf k&1 — no aliasing.
// Consumer ds_reads complete before its stores issue (data dep), so producers
// overwriting buf (k+1)&1 after barrier k is race-free.
// ---------------------------------------------------------------------------
__global__ void __launch_bounds__(256, 1)
poly_pc(const float* __restrict__ x, float* __restrict__ out) {
    __shared__ __align__(16) float lds[2][PROWS * NCOLS];   // 124,032 B -> 1 block/CU

    const int tid = threadIdx.x;
    const int rowbase = blockIdx.x * (NPASS * PROWS);       // 256 rows per block

    if (tid < 128) {
        // ---------------- producers ----------------
        const int prow  = tid & 15;          // row within half-pass
        const int range = tid >> 4;          // 0..7
        // preload x-row for pass 0
        const floatx4* xv = (const floatx4*)(x + (size_t)(rowbase + prow) * NFEAT);
        floatx4 a0 = xv[0], a1 = xv[1], a2 = xv[2], a3 = xv[3];

        for (int p = 0; p < NPASS; ++p) {
            float xr[NFEAT] = {a0[0],a0[1],a0[2],a0[3], a1[0],a1[1],a1[2],a1[3],
                               a2[0],a2[1],a2[2],a2[3], a3[0],a3[1],a3[2],a3[3]};
            // prefetch next pass's x-row; latency hides under compute + barrier
            if (p + 1 < NPASS) {
                const floatx4* nv = (const floatx4*)
                    (x + (size_t)(rowbase + (p + 1) * PROWS + prow) * NFEAT);
                a0 = nv[0]; a1 = nv[1]; a2 = nv[2]; a3 = nv[3];
            }
            compute_dispatch(range, xr, &lds[p & 1][prow * NCOLS]);
            asm volatile("s_waitcnt lgkmcnt(0)" ::: "memory");  // ds_writes visible
            __builtin_amdgcn_s_barrier();                        // barrier p
        }
    } else {
        // ---------------- consumers ----------------
        const int ctid = tid - 128;          // 0..127
        for (int p = 0; p < NPASS; ++p) {
            __builtin_amdgcn_s_barrier();                        // barrier p
            const floatx4* src = (const floatx4*)lds[p & 1];
            floatx4* dst = (floatx4*)(out + (size_t)(rowbase + p * PROWS) * NCOLS);
            #pragma unroll 4
            for (int g4 = ctid; g4 < PASS_F4; g4 += 128)         // ~30 iters
                dst[g4] = src[g4];
        }
    }
}

extern "C" void kernel_launch(void* const* d_in, const int* in_sizes, int n_in,
                              void* d_out, int out_size, void* d_ws, size_t ws_size,
                              hipStream_t stream) {
    const float* x = (const float*)d_in[0];
    float* out = (float*)d_out;
    // 256 persistent blocks (1 per CU), 16 double-buffered half-passes each.
    poly_pc<<<256, 256, 0, stream>>>(x, out);
}

// Round 13
// 47.026 us; speedup vs baseline: 1.4136x; 1.4136x over previous
//
#include <hip/hip_runtime.h>
#include <stdint.h>

#define NFEAT 16
#define NCOLS 969            // 1 bias + 16 deg1 + 136 deg2 + 816 deg3
#define NROWS 65536
#define PASS_ROWS 32
#define TILE_ROWS 64
#define TILES_PER_BLOCK 4    // 256 blocks * 4 tiles * 64 rows = 65536
#define PASS_ELEMS (PASS_ROWS * NCOLS)   // 31008 dwords, flat-contiguous in out
#define NTHREADS 512

typedef float floatx4 __attribute__((ext_vector_type(4)));

// ---------------------------------------------------------------------------
// Static compute of cols [CBASE, CEND) of one row into packed LDS row.
// All 969 columns emitted in sklearn/jax reference order (verified absmax 0.0
// R1/R3-R12); out-of-range emits are compile-time dead. Scalar ds_write_b32:
// packed stride 969 -> banks (9*row + col) % 32; 32 rows x stride 9 (coprime
// with 32) covers all banks exactly once per col: conflict-free.
// 60-col bodies keep the live set ~100-150 VGPRs -> fits the 256 cap of
// __launch_bounds__(512,2) without spilling (R9's spill came from its
// fully-unrolled store, not body size).
// ---------------------------------------------------------------------------
template<int CBASE, int CEND>
__device__ __forceinline__ void compute_range(const float* xr, float* ldsrow) {
    int col = 0;
#define EMIT(P) do { if (col >= CBASE && col < CEND) ldsrow[col] = (P); ++col; } while (0)
    EMIT(1.0f);                                   // bias
    #pragma unroll
    for (int i = 0; i < NFEAT; ++i) EMIT(xr[i]);  // degree 1
    #pragma unroll
    for (int i = 0; i < NFEAT; ++i)               // degree 2
        #pragma unroll
        for (int j = i; j < NFEAT; ++j) EMIT(xr[i] * xr[j]);
    #pragma unroll
    for (int i = 0; i < NFEAT; ++i)               // degree 3 (reuses x_i*x_j via CSE)
        #pragma unroll
        for (int j = i; j < NFEAT; ++j)
            #pragma unroll
            for (int k = j; k < NFEAT; ++k) EMIT((xr[i] * xr[j]) * xr[k]);
#undef EMIT
}

__device__ __forceinline__ void compute_dispatch(int range, const float* xr, float* ldsrow) {
    switch (range) {   // uniform per 32-lane half-wave -> 2 serial 32-lane bodies/wave
        case  0: compute_range<  0,  60>(xr, ldsrow); break;
        case  1: compute_range< 60, 120>(xr, ldsrow); break;
        case  2: compute_range<120, 180>(xr, ldsrow); break;
        case  3: compute_range<180, 240>(xr, ldsrow); break;
        case  4: compute_range<240, 300>(xr, ldsrow); break;
        case  5: compute_range<300, 360>(xr, ldsrow); break;
        case  6: compute_range<360, 420>(xr, ldsrow); break;
        case  7: compute_range<420, 480>(xr, ldsrow); break;
        case  8: compute_range<480, 540>(xr, ldsrow); break;
        case  9: compute_range<540, 600>(xr, ldsrow); break;
        case 10: compute_range<600, 660>(xr, ldsrow); break;
        case 11: compute_range<660, 720>(xr, ldsrow); break;
        case 12: compute_range<720, 780>(xr, ldsrow); break;
        case 13: compute_range<780, 840>(xr, ldsrow); break;
        case 14: compute_range<840, 900>(xr, ldsrow); break;
        case 15: compute_range<900, 969>(xr, ldsrow); break;
    }
}

// Store phase = flat copy of the packed LDS image (R11's proven shape):
// ds_read_b128 + global_store_dwordx4, both 16B-aligned. 8 waves -> 15-16
// iterations/thread; 2x the store-issue margin of R11's 4 waves.
__device__ __forceinline__ void store_pass(float* __restrict__ out, int rowbase,
                                           int tid, const float* lds) {
    floatx4* dst4 = (floatx4*)(out + (size_t)rowbase * NCOLS);
    const floatx4* lds4 = (const floatx4*)lds;
    #pragma unroll 4
    for (int g4 = tid; g4 < PASS_ELEMS / 4; g4 += NTHREADS)   // 7752 groups
        dst4[g4] = lds4[g4];
}

// Raw barrier WITHOUT vmcnt(0) drain: LDS visibility needs only lgkmcnt(0);
// in-flight global stores drain across the barrier while next pass computes.
__device__ __forceinline__ void lds_barrier() {
    asm volatile("s_waitcnt lgkmcnt(0)" ::: "memory");
    __builtin_amdgcn_s_barrier();
}

__global__ void __launch_bounds__(NTHREADS, 2)
poly_rows(const float* __restrict__ x, float* __restrict__ out) {
    __shared__ __align__(16) float lds[PASS_ROWS * NCOLS];   // 124,032 B -> 1 block/CU

    const int tid   = threadIdx.x;
    const int lrow  = tid & 31;                  // row within pass
    const int range = tid >> 5;                  // 0..15, uniform per 32-lane group
    float* ldsrow = &lds[lrow * NCOLS];

    for (int it = 0; it < TILES_PER_BLOCK; ++it) {
        const int row0 = (blockIdx.x * TILES_PER_BLOCK + it) * TILE_ROWS;

        // Two x-rows per lane (pass A and pass B of this 64-row tile).
        const floatx4* xa = (const floatx4*)(x + (size_t)(row0 + lrow) * NFEAT);
        const floatx4* xb = (const floatx4*)(x + (size_t)(row0 + 32 + lrow) * NFEAT);
        floatx4 a0 = xa[0], a1 = xa[1], a2 = xa[2], a3 = xa[3];
        floatx4 b0 = xb[0], b1 = xb[1], b2 = xb[2], b3 = xb[3];
        float xrA[NFEAT] = {a0[0],a0[1],a0[2],a0[3], a1[0],a1[1],a1[2],a1[3],
                            a2[0],a2[1],a2[2],a2[3], a3[0],a3[1],a3[2],a3[3]};
        float xrB[NFEAT] = {b0[0],b0[1],b0[2],b0[3], b1[0],b1[1],b1[2],b1[3],
                            b2[0],b2[1],b2[2],b2[3], b3[0],b3[1],b3[2],b3[3]};

        // ---- pass A: rows row0..row0+31 ----
        compute_dispatch(range, xrA, ldsrow);
        lds_barrier();
        store_pass(out, row0, tid, lds);
        lds_barrier();
        // ---- pass B: rows row0+32..row0+63 ----
        compute_dispatch(range, xrB, ldsrow);
        lds_barrier();
        store_pass(out, row0 + 32, tid, lds);
        lds_barrier();
    }
}

extern "C" void kernel_launch(void* const* d_in, const int* in_sizes, int n_in,
                              void* d_out, int out_size, void* d_ws, size_t ws_size,
                              hipStream_t stream) {
    const float* x = (const float*)d_in[0];
    float* out = (float*)d_out;
    // 256 blocks (1 per CU, LDS-capped), 8 waves each, 4 tiles of 64 rows.
    poly_rows<<<256, NTHREADS, 0, stream>>>(x, out);
}